// Round 5
// baseline (343.452 us; speedup 1.0000x reference)
//
#include <hip/hip_runtime.h>
#include <math.h>

// Qwen2 block: B=8 L=16 E=2048 S0=4096 F=5632 H=16 HKV=2 D=128
#define MM 128
#define EE 2048
#define FF 5632
#define S0C 4096
#define STOT 4112
#define NSPLIT 32
#define LDQKV 2560

typedef float f32x4 __attribute__((ext_vector_type(4)));
typedef short s16x8 __attribute__((ext_vector_type(8)));

#define MFMA16(a, b, c) __builtin_amdgcn_mfma_f32_16x16x32_bf16(a, b, c, 0, 0, 0)

// round-half-up fp32->bf16 (1 VALU); pack two via v_perm (3 VALU / 2 elems)
__device__ __forceinline__ unsigned short f2bfu(float f) {
    return (unsigned short)((__float_as_uint(f) + 0x8000u) >> 16);
}
__device__ __forceinline__ unsigned pk2(float lo, float hi) {
    return __builtin_amdgcn_perm(__float_as_uint(hi) + 0x8000u,
                                 __float_as_uint(lo) + 0x8000u, 0x07060302u);
}
__device__ __forceinline__ float bf2f(unsigned short u) {
    return __uint_as_float(((unsigned)u) << 16);
}

// A-fragment layout: element (row, k) of A[128][K] lives at
//   (k>>5)*4096 + ((k>>3)&3)*1024 + row*8 + (k&7)    (shorts)
// so a wave's A-frag load (quad = k-octet, l15 = row%16) is 4x256B contiguous.

// ---------------- RMSNorm -> bf16 fragged A ----------------
__global__ __launch_bounds__(256) void rmsnorm_bf16(const float* __restrict__ x,
                                                    const float* __restrict__ w,
                                                    unsigned short* __restrict__ out) {
    int row = blockIdx.x;
    int t = threadIdx.x;
    const float4* xr = (const float4*)(x + row * EE);
    float4 a = xr[2 * t];
    float4 b = xr[2 * t + 1];
    float ss = a.x*a.x + a.y*a.y + a.z*a.z + a.w*a.w
             + b.x*b.x + b.y*b.y + b.z*b.z + b.w*b.w;
    #pragma unroll
    for (int o = 32; o > 0; o >>= 1) ss += __shfl_down(ss, o);
    __shared__ float red[4];
    if ((t & 63) == 0) red[t >> 6] = ss;
    __syncthreads();
    float tot = red[0] + red[1] + red[2] + red[3];
    float inv = rsqrtf(tot * (1.0f / (float)EE) + 1e-6f);
    const float4* wr = (const float4*)w;
    float4 w0 = wr[2 * t], w1 = wr[2 * t + 1];
    float4 o0, o1;
    o0.x = a.x*inv*w0.x; o0.y = a.y*inv*w0.y; o0.z = a.z*inv*w0.z; o0.w = a.w*inv*w0.w;
    o1.x = b.x*inv*w1.x; o1.y = b.y*inv*w1.y; o1.z = b.z*inv*w1.z; o1.w = b.w*inv*w1.w;
    unsigned short* dst = out + (t >> 2) * 4096 + (t & 3) * 1024 + row * 8;
    *(uint4*)dst = make_uint4(pk2(o0.x, o0.y), pk2(o0.z, o0.w),
                              pk2(o1.x, o1.y), pk2(o1.z, o1.w));
}

// ---------------- barrier-free deep-pipelined streaming GEMM ----------------
// wave = 128 rows x 16 cols. A bf16-fragged (L1/L2-resident), W fp32 streamed from HBM.
// Software pipeline: W prefetch depth 4 (HBM latency), A depth 2 (cache latency).
// P[sk][128][N] fp32 partials; k-slice = blockIdx.y * (NK*32).
template<int NK>
__global__ __launch_bounds__(256) void gemm_stream(const unsigned short* __restrict__ Af,
                                                   const float* __restrict__ W0,
                                                   const float* __restrict__ W1,
                                                   const float* __restrict__ W2,
                                                   int cut1, int cut2,
                                                   int K, float* __restrict__ P, int N) {
    constexpr int PFW = NK < 4 ? NK : 4;
    constexpr int PFA = NK < 2 ? NK : 2;
    int t = threadIdx.x;
    int wv = t >> 6, lane = t & 63, quad = lane >> 4, l15 = lane & 15;
    int nb = blockIdx.x * 64 + wv * 16;
    const float* Wm; int nn;
    if (nb < cut1)      { Wm = W0; nn = nb; }
    else if (nb < cut2) { Wm = W1; nn = nb - cut1; }
    else                { Wm = W2; nn = nb - cut2; }
    int k0 = blockIdx.y * (NK * 32);
    const float* Wr = Wm + (size_t)(nn + l15) * K + k0 + quad * 8;
    const unsigned short* ap = Af + (k0 >> 5) * 4096 + quad * 1024 + l15 * 8;

    float4 wb0[PFW], wb1[PFW];
    s16x8 ab[PFA][8];
    #pragma unroll
    for (int p = 0; p < PFW; p++) {
        wb0[p] = *(const float4*)(Wr + p * 32);
        wb1[p] = *(const float4*)(Wr + p * 32 + 4);
    }
    #pragma unroll
    for (int p = 0; p < PFA; p++)
        #pragma unroll
        for (int g = 0; g < 8; g++)
            ab[p][g] = *(const s16x8*)(ap + p * 4096 + g * 128);

    f32x4 acc[8];
    #pragma unroll
    for (int g = 0; g < 8; g++) acc[g] = (f32x4){0.f, 0.f, 0.f, 0.f};

    #pragma unroll
    for (int ks = 0; ks < NK; ks++) {
        float4 w0 = wb0[ks % PFW], w1 = wb1[ks % PFW];
        union { unsigned u[4]; s16x8 v; } bu;
        bu.u[0] = pk2(w0.x, w0.y);
        bu.u[1] = pk2(w0.z, w0.w);
        bu.u[2] = pk2(w1.x, w1.y);
        bu.u[3] = pk2(w1.z, w1.w);
        s16x8 bf = bu.v;
        #pragma unroll
        for (int g = 0; g < 8; g++)
            acc[g] = MFMA16(ab[ks % PFA][g], bf, acc[g]);
        if (ks + PFW < NK) {
            wb0[ks % PFW] = *(const float4*)(Wr + (ks + PFW) * 32);
            wb1[ks % PFW] = *(const float4*)(Wr + (ks + PFW) * 32 + 4);
        }
        if (ks + PFA < NK) {
            const unsigned short* app = ap + (ks + PFA) * 4096;
            #pragma unroll
            for (int g = 0; g < 8; g++)
                ab[ks % PFA][g] = *(const s16x8*)(app + g * 128);
        }
    }

    size_t pb = (size_t)blockIdx.y * MM * N + nb;
    #pragma unroll
    for (int g = 0; g < 8; g++)
        #pragma unroll
        for (int r = 0; r < 4; r++)
            P[pb + (size_t)(g * 16 + quad * 4 + r) * N + l15] = acc[g][r];
}

// ---------------- reduce kernels ----------------
__global__ __launch_bounds__(256) void reduce_qkv(const float* __restrict__ P,
                                                  const float* __restrict__ bq,
                                                  const float* __restrict__ bk,
                                                  const float* __restrict__ bv,
                                                  float* __restrict__ C) {
    int e4 = (blockIdx.x * 256 + threadIdx.x) * 4;   // over 128*2560
    f32x4 s = {0.f, 0.f, 0.f, 0.f};
    #pragma unroll
    for (int sx = 0; sx < 8; sx++)
        s += *(const f32x4*)(P + (size_t)sx * (MM * LDQKV) + e4);
    int c = e4 % LDQKV;
    const float* bptr; int cl;
    if (c < 2048)      { bptr = bq; cl = c; }
    else if (c < 2304) { bptr = bk; cl = c - 2048; }
    else               { bptr = bv; cl = c - 2304; }
    s += *(const f32x4*)(bptr + cl);
    *(f32x4*)(C + e4) = s;
}

__global__ __launch_bounds__(256) void reduce_res(const float* __restrict__ P,
                                                  const float* __restrict__ res,
                                                  float* __restrict__ C) {
    int e4 = (blockIdx.x * 256 + threadIdx.x) * 4;   // over 128*2048
    f32x4 s = *(const f32x4*)(res + e4);
    #pragma unroll
    for (int sx = 0; sx < 8; sx++)
        s += *(const f32x4*)(P + (size_t)sx * (MM * EE) + e4);
    *(f32x4*)(C + e4) = s;
}

// gate|up partials -> silu(g)*u -> bf16 fragged A (for down-proj, K=5632)
__global__ __launch_bounds__(256) void reduce_gateup(const float* __restrict__ P,
                                                     unsigned short* __restrict__ gbf) {
    int e4 = (blockIdx.x * 256 + threadIdx.x) * 4;   // over 128*5632
    int m = e4 / FF, f = e4 % FF;
    f32x4 g = {0.f,0.f,0.f,0.f}, u = g;
    #pragma unroll
    for (int sx = 0; sx < 2; sx++) {
        size_t base = (size_t)sx * (MM * 11264) + (size_t)m * 11264;
        g += *(const f32x4*)(P + base + f);
        u += *(const f32x4*)(P + base + 5632 + f);
    }
    f32x4 r;
    #pragma unroll
    for (int j = 0; j < 4; j++)
        r[j] = g[j] / (1.f + __expf(-g[j])) * u[j];
    unsigned short* dst = gbf + (f >> 5) * 4096 + ((f >> 3) & 3) * 1024 + m * 8 + (f & 7);
    *(uint2*)dst = make_uint2(pk2(r[0], r[1]), pk2(r[2], r[3]));
}

// ---------------- RoPE (qkv packed buffer, ld=2560) ----------------
__global__ __launch_bounds__(256) void rope_kernel(float* __restrict__ qkv,
                                                   const int* __restrict__ offp) {
    int t = blockIdx.x * 256 + threadIdx.x;
    int off = offp[0];
    float* ptr; int dh; int l;
    if (t < 131072) {                   // q: 128 tok * 16 heads * 64
        int token = t >> 10;
        int rem = t & 1023;
        int hh = rem >> 6;
        dh = rem & 63;
        ptr = qkv + token * LDQKV + hh * 128;
        l = token & 15;
    } else {                            // k: 128 tok * 2 kvheads * 64
        int t2 = t - 131072;
        int token = t2 >> 7;
        int rem = t2 & 127;
        int hh = rem >> 6;
        dh = rem & 63;
        ptr = qkv + 2048 + token * LDQKV + hh * 128;
        l = token & 15;
    }
    float pos = (float)(off + l);
    float inv = exp2f(-(float)dh * (13.287712379549449f / 64.0f));
    float ang = pos * inv;
    float s, c;
    sincosf(ang, &s, &c);
    float x0 = ptr[dh], x1 = ptr[dh + 64];
    ptr[dh]      = x0 * c - x1 * s;
    ptr[dh + 64] = x1 * c + x0 * s;
}

// ---------------- Flash-decode MFMA attention ----------------
__global__ __launch_bounds__(256) void attn_kernel(const float* __restrict__ qkv,
                                                   const float* __restrict__ ck,
                                                   const float* __restrict__ cv,
                                                   const int* __restrict__ offp,
                                                   unsigned short* __restrict__ Os,
                                                   float* __restrict__ Mw,
                                                   float* __restrict__ Lw) {
    __shared__ __align__(16) char smem[35840];
    short* Qs = (short*)smem;              // 128 rows, stride 136
    short* Ks = (short*)smem;              // 32 rows, stride 136
    short* Vt = (short*)(smem + 8704);     // 128 d-rows x 32, stride 40
    short* Ps = (short*)(smem + 18944);    // 128 rows x 32, stride 40
    float* mrow = (float*)(smem + 34816);
    float* lrow = (float*)(smem + 35328);

    int t = threadIdx.x;
    int wv = t >> 6, lane = t & 63, quad = lane >> 4, l15 = lane & 15;
    int split = blockIdx.x;
    int bkv = blockIdx.y;
    int b = bkv >> 1, kv = bkv & 1;
    int off = offp[0];
    const float scl = 0.08838834764831845f;

    {
        int row = t >> 1, half = t & 1;
        int l = row & 15, hg = row >> 4;
        const float* qp = qkv + (size_t)(b * 16 + l) * LDQKV + (kv * 8 + hg) * 128 + half * 64;
        unsigned* Qu = (unsigned*)(Qs + row * 136 + half * 64);
        #pragma unroll
        for (int i = 0; i < 8; i++) {
            float4 v4 = *(const float4*)(qp + i * 8);
            float4 v5 = *(const float4*)(qp + i * 8 + 4);
            *(uint4*)(Qu + i * 4) = make_uint4(pk2(v4.x*scl, v4.y*scl), pk2(v4.z*scl, v4.w*scl),
                                               pk2(v5.x*scl, v5.y*scl), pk2(v5.z*scl, v5.w*scl));
        }
    }
    if (t < 128) { mrow[t] = -1e30f; lrow[t] = 0.f; }
    __syncthreads();

    s16x8 qf[2][4];
    #pragma unroll
    for (int mt = 0; mt < 2; mt++)
        #pragma unroll
        for (int ks = 0; ks < 4; ks++)
            qf[mt][ks] = *(const s16x8*)(Qs + (wv * 32 + mt * 16 + l15) * 136 + ks * 32 + quad * 8);

    f32x4 oacc[2][8];
    #pragma unroll
    for (int mt = 0; mt < 2; mt++)
        #pragma unroll
        for (int nt = 0; nt < 8; nt++)
            oacc[mt][nt] = (f32x4){0.f, 0.f, 0.f, 0.f};

    int s_begin = split * 128;
    int s_end = (split == NSPLIT - 1) ? STOT : s_begin + 128;

    for (int s0 = s_begin; s0 < s_end; s0 += 32) {
        int cs = min(32, s_end - s0);
        __syncthreads();
        {
            int key = t >> 3, dc = t & 7;
            int s = s0 + key; if (s > STOT - 1) s = STOT - 1;
            const float* kp = (s < S0C)
                ? ck + ((size_t)(b * 2 + kv) * S0C + s) * 128 + dc * 16
                : qkv + 2048 + (size_t)(b * 16 + (s - S0C)) * LDQKV + kv * 128 + dc * 16;
            float4 k0v = *(const float4*)(kp);
            float4 k1v = *(const float4*)(kp + 4);
            float4 k2v = *(const float4*)(kp + 8);
            float4 k3v = *(const float4*)(kp + 12);
            unsigned* Ku = (unsigned*)(Ks + key * 136 + dc * 16);
            *(uint4*)(Ku)     = make_uint4(pk2(k0v.x,k0v.y), pk2(k0v.z,k0v.w), pk2(k1v.x,k1v.y), pk2(k1v.z,k1v.w));
            *(uint4*)(Ku + 4) = make_uint4(pk2(k2v.x,k2v.y), pk2(k2v.z,k2v.w), pk2(k3v.x,k3v.y), pk2(k3v.z,k3v.w));
        }
        {
            int c = t & 31, dch = t >> 5;
            int s = s0 + c; if (s > STOT - 1) s = STOT - 1;
            const float* vp = (s < S0C)
                ? cv + ((size_t)(b * 2 + kv) * S0C + s) * 128 + dch * 16
                : qkv + 2304 + (size_t)(b * 16 + (s - S0C)) * LDQKV + kv * 128 + dch * 16;
            float vv[16];
            *(float4*)(vv)      = *(const float4*)(vp);
            *(float4*)(vv + 4)  = *(const float4*)(vp + 4);
            *(float4*)(vv + 8)  = *(const float4*)(vp + 8);
            *(float4*)(vv + 12) = *(const float4*)(vp + 12);
            #pragma unroll
            for (int j = 0; j < 16; j++)
                Vt[(dch * 16 + j) * 40 + c] = (short)f2bfu(vv[j]);
        }
        __syncthreads();
        f32x4 sa[2][2];
        sa[0][0] = (f32x4){0.f,0.f,0.f,0.f}; sa[0][1] = sa[0][0];
        sa[1][0] = sa[0][0];                 sa[1][1] = sa[0][0];
        #pragma unroll
        for (int ks = 0; ks < 4; ks++) {
            #pragma unroll
            for (int nt = 0; nt < 2; nt++) {
                s16x8 kf = *(const s16x8*)(Ks + (nt * 16 + l15) * 136 + ks * 32 + quad * 8);
                sa[0][nt] = MFMA16(qf[0][ks], kf, sa[0][nt]);
                sa[1][nt] = MFMA16(qf[1][ks], kf, sa[1][nt]);
            }
        }
        float alpha[2][4];
        #pragma unroll
        for (int mt = 0; mt < 2; mt++) {
            #pragma unroll
            for (int r = 0; r < 4; r++) {
                int row = wv * 32 + mt * 16 + quad * 4 + r;
                int ltok = row & 15;
                float s0v = sa[mt][0][r];
                float s1v = sa[mt][1][r];
                int g0 = s0 + l15, g1 = s0 + 16 + l15;
                bool ok0 = (l15 < cs) && (g0 <= off + ltok);
                bool ok1 = (16 + l15 < cs) && (g1 <= off + ltok);
                s0v = ok0 ? s0v : -3e38f;
                s1v = ok1 ? s1v : -3e38f;
                float mc = fmaxf(s0v, s1v);
                mc = fmaxf(mc, __shfl_xor(mc, 1));
                mc = fmaxf(mc, __shfl_xor(mc, 2));
                mc = fmaxf(mc, __shfl_xor(mc, 4));
                mc = fmaxf(mc, __shfl_xor(mc, 8));
                float mold = mrow[row];
                float mnew = fmaxf(mold, mc);
                float al = __expf(mold - mnew);
                float p0 = __expf(s0v - mnew);
                float p1 = __expf(s1v - mnew);
                float rs = p0 + p1;
                rs += __shfl_xor(rs, 1);
                rs += __shfl_xor(rs, 2);
                rs += __shfl_xor(rs, 4);
                rs += __shfl_xor(rs, 8);
                if (l15 == 0) { mrow[row] = mnew; lrow[row] = lrow[row] * al + rs; }
                alpha[mt][r] = al;
                Ps[row * 40 + l15] = (short)f2bfu(p0);
                Ps[row * 40 + 16 + l15] = (short)f2bfu(p1);
            }
        }
        #pragma unroll
        for (int mt = 0; mt < 2; mt++)
            #pragma unroll
            for (int nt = 0; nt < 8; nt++)
                #pragma unroll
                for (int r = 0; r < 4; r++)
                    oacc[mt][nt][r] *= alpha[mt][r];
        s16x8 pf0 = *(const s16x8*)(Ps + (wv * 32 + l15) * 40 + quad * 8);
        s16x8 pf1 = *(const s16x8*)(Ps + (wv * 32 + 16 + l15) * 40 + quad * 8);
        #pragma unroll
        for (int nt = 0; nt < 8; nt++) {
            s16x8 vf = *(const s16x8*)(Vt + (nt * 16 + l15) * 40 + quad * 8);
            oacc[0][nt] = MFMA16(pf0, vf, oacc[0][nt]);
            oacc[1][nt] = MFMA16(pf1, vf, oacc[1][nt]);
        }
    }

    __syncthreads();
    size_t obase = (size_t)(split * 16 + bkv) * 128;
    #pragma unroll
    for (int mt = 0; mt < 2; mt++)
        #pragma unroll
        for (int nt = 0; nt < 8; nt++)
            #pragma unroll
            for (int r = 0; r < 4; r++) {
                int row = wv * 32 + mt * 16 + quad * 4 + r;
                int d = nt * 16 + l15;
                Os[(obase + row) * 128 + d] = f2bfu(oacc[mt][nt][r]);
            }
    if (t < 128) { Mw[obase + t] = mrow[t]; Lw[obase + t] = lrow[t]; }
}

// ---------------- merge split partials -> bf16 fragged A (for o-proj, K=2048) ------
__global__ __launch_bounds__(256) void merge_kernel(const unsigned short* __restrict__ Os,
                                                    const float* __restrict__ Mw,
                                                    const float* __restrict__ Lw,
                                                    unsigned short* __restrict__ obf) {
    int blk = blockIdx.x;
    int bkv = blk >> 3, rg = blk & 7;
    int b = bkv >> 1, kv = bkv & 1;
    int t = threadIdx.x;
    int rowl = t >> 4;
    int row = rg * 16 + rowl;
    int dchunk = (t & 15) * 8;
    float M = -3e38f;
    for (int s = 0; s < NSPLIT; s++)
        M = fmaxf(M, Mw[((size_t)s * 16 + bkv) * 128 + row]);
    float denom = 0.f;
    float o[8];
    #pragma unroll
    for (int j = 0; j < 8; j++) o[j] = 0.f;
    for (int s = 0; s < NSPLIT; s++) {
        size_t base = ((size_t)s * 16 + bkv) * 128 + row;
        float w = __expf(Mw[base] - M);
        denom += Lw[base] * w;
        uint4 u = *(const uint4*)(Os + base * 128 + dchunk);
        o[0] += w * bf2f((unsigned short)(u.x & 0xffff));
        o[1] += w * bf2f((unsigned short)(u.x >> 16));
        o[2] += w * bf2f((unsigned short)(u.y & 0xffff));
        o[3] += w * bf2f((unsigned short)(u.y >> 16));
        o[4] += w * bf2f((unsigned short)(u.z & 0xffff));
        o[5] += w * bf2f((unsigned short)(u.z >> 16));
        o[6] += w * bf2f((unsigned short)(u.w & 0xffff));
        o[7] += w * bf2f((unsigned short)(u.w >> 16));
    }
    float inv = 1.f / denom;
    #pragma unroll
    for (int j = 0; j < 8; j++) o[j] *= inv;
    int m = b * 16 + rowl;
    int e0 = (kv * 8 + rg) * 128 + dchunk;
    unsigned short* dst = obf + (e0 >> 5) * 4096 + ((e0 >> 3) & 3) * 1024 + m * 8;
    *(uint4*)dst = make_uint4(pk2(o[0], o[1]), pk2(o[2], o[3]),
                              pk2(o[4], o[5]), pk2(o[6], o[7]));
}

// ---------------- launch ----------------
extern "C" void kernel_launch(void* const* d_in, const int* in_sizes, int n_in,
                              void* d_out, int out_size, void* d_ws, size_t ws_size,
                              hipStream_t stream) {
    const float* x        = (const float*)d_in[0];
    const float* cache_k  = (const float*)d_in[1];
    const float* cache_v  = (const float*)d_in[2];
    const float* wq       = (const float*)d_in[3];
    const float* wk       = (const float*)d_in[4];
    const float* wv       = (const float*)d_in[5];
    const float* wo       = (const float*)d_in[6];
    const float* bq       = (const float*)d_in[7];
    const float* bk       = (const float*)d_in[8];
    const float* bv       = (const float*)d_in[9];
    const float* w_gate   = (const float*)d_in[10];
    const float* w_up     = (const float*)d_in[11];
    const float* w_down   = (const float*)d_in[12];
    const float* w_in_ln  = (const float*)d_in[13];
    const float* w_post_ln= (const float*)d_in[14];
    const int*   offp     = (const int*)d_in[15];
    float* out = (float*)d_out;

    float* ws = (float*)d_ws;
    float* qkvb = ws;                                   // 327680
    float* hb   = ws + 327680;                          // 262144 -> 589824
    unsigned short* xnf = (unsigned short*)(ws + 589824);   // 131072 f
    unsigned short* hnf = (unsigned short*)(ws + 720896);   // 131072 f
    unsigned short* obf = (unsigned short*)(ws + 851968);   // 131072 f
    unsigned short* gbf = (unsigned short*)(ws + 983040);   // 360448 f
    float* R = ws + 1343488;                            // P / Os+Mw+Lw
    float* P = R;
    unsigned short* Osw = (unsigned short*)R;
    float* Mw = R + 4194304;
    float* Lw = R + 4259840;                            // end: 5668864 f = 22.7 MB

    const int BIG = 1 << 30;

    // 1) input RMSNorm -> bf16 fragged
    rmsnorm_bf16<<<MM, 256, 0, stream>>>(x, w_in_ln, xnf);
    // 2) QKV: N=2560 (q|k|v), K=2048, SK=8 (NK=8) -> 320 blocks
    gemm_stream<8><<<dim3(40, 8), 256, 0, stream>>>(xnf, wq, wk, wv, 2048, 2304, 2048, P, LDQKV);
    reduce_qkv<<<320, 256, 0, stream>>>(P, bq, bk, bv, qkvb);
    rope_kernel<<<576, 256, 0, stream>>>(qkvb, offp);
    attn_kernel<<<dim3(NSPLIT, 16), 256, 0, stream>>>(qkvb, cache_k, cache_v, offp, Osw, Mw, Lw);
    merge_kernel<<<128, 256, 0, stream>>>(Osw, Mw, Lw, obf);
    // 3) O-proj: N=2048, K=2048, SK=8 (NK=8) -> 256 blocks
    gemm_stream<8><<<dim3(32, 8), 256, 0, stream>>>(obf, wo, wo, wo, BIG, BIG, 2048, P, EE);
    reduce_res<<<256, 256, 0, stream>>>(P, x, hb);
    // 4) post RMSNorm -> bf16 fragged
    rmsnorm_bf16<<<MM, 256, 0, stream>>>(hb, w_post_ln, hnf);
    // 5) Gate|Up: N=11264, K=2048, SK=2 (NK=32) -> 352 blocks
    gemm_stream<32><<<dim3(176, 2), 256, 0, stream>>>(hnf, w_gate, w_up, w_up, 5632, BIG, 2048, P, 11264);
    reduce_gateup<<<704, 256, 0, stream>>>(P, gbf);
    // 6) Down: N=2048, K=5632, SK=8 (NK=22) -> 256 blocks
    gemm_stream<22><<<dim3(32, 8), 256, 0, stream>>>(gbf, w_down, w_down, w_down, BIG, BIG, 5632, P, EE);
    reduce_res<<<256, 256, 0, stream>>>(P, hb, out);
}